// Round 1
// baseline (650.839 us; speedup 1.0000x reference)
//
#include <hip/hip_runtime.h>

// GNN27: two-branch diffusion GCN (N=8192, F_IN=11, F1=16, F2=32) + multi-head
// tanh-attention pooling. All fp32. Memory-bound on the two 268MB adjacencies,
// each streamed twice (layer1, layer2) -> 1.07GB HBM floor ~170us.

constexpr int N = 8192;

// ---------------- kernel 1: P1 = x @ W1   ([N,11] @ [11,16]) ----------------
__global__ void k_dense_in(const float* __restrict__ x0, const float* __restrict__ x1,
                           const float* __restrict__ W0, const float* __restrict__ W1,
                           float* __restrict__ o0, float* __restrict__ o1) {
    const int branch = blockIdx.y;
    const float* __restrict__ x = branch ? x1 : x0;
    const float* __restrict__ W = branch ? W1 : W0;
    float* __restrict__ o = branch ? o1 : o0;
    __shared__ float sW[11 * 16];
    if (threadIdx.x < 176) sW[threadIdx.x] = W[threadIdx.x];
    __syncthreads();
    const int n = blockIdx.x * blockDim.x + threadIdx.x;  // grid.x*256 == N exactly
    float xr[11];
#pragma unroll
    for (int j = 0; j < 11; ++j) xr[j] = x[n * 11 + j];
    float acc[16];
#pragma unroll
    for (int f = 0; f < 16; ++f) acc[f] = 0.f;
#pragma unroll
    for (int j = 0; j < 11; ++j)
#pragma unroll
        for (int f = 0; f < 16; ++f) acc[f] += xr[j] * sW[j * 16 + f];
#pragma unroll
    for (int q = 0; q < 4; ++q) {
        float4 r = make_float4(acc[q * 4 + 0], acc[q * 4 + 1], acc[q * 4 + 2], acc[q * 4 + 3]);
        *reinterpret_cast<float4*>(&o[n * 16 + q * 4]) = r;
    }
}

// ---------------- kernel 3: P2 = H1 @ W2   ([N,16] @ [16,32]) ----------------
__global__ void k_dense_mid(const float* __restrict__ h0, const float* __restrict__ h1,
                            const float* __restrict__ W0, const float* __restrict__ W1,
                            float* __restrict__ o0, float* __restrict__ o1) {
    const int branch = blockIdx.y;
    const float* __restrict__ h = branch ? h1 : h0;
    const float* __restrict__ W = branch ? W1 : W0;
    float* __restrict__ o = branch ? o1 : o0;
    __shared__ float sW[16 * 32];
    for (int i = threadIdx.x; i < 512; i += blockDim.x) sW[i] = W[i];
    __syncthreads();
    const int n = blockIdx.x * blockDim.x + threadIdx.x;
    float hr[16];
#pragma unroll
    for (int q = 0; q < 4; ++q)
        *reinterpret_cast<float4*>(&hr[q * 4]) =
            *reinterpret_cast<const float4*>(&h[n * 16 + q * 4]);
    float acc[32];
#pragma unroll
    for (int f = 0; f < 32; ++f) acc[f] = 0.f;
#pragma unroll
    for (int j = 0; j < 16; ++j)
#pragma unroll
        for (int f = 0; f < 32; ++f) acc[f] += hr[j] * sW[j * 32 + f];
#pragma unroll
    for (int q = 0; q < 8; ++q) {
        float4 r = make_float4(acc[q * 4 + 0], acc[q * 4 + 1], acc[q * 4 + 2], acc[q * 4 + 3]);
        *reinterpret_cast<float4*>(&o[n * 32 + q * 4]) = r;
    }
}

// -------- kernels 2 & 4: H = relu(A @ P + b), A [N,N] streamed from HBM ------
// Block = 256 thr = 4 waves, 32 rows/block (8 rows/wave). Lane = 16 k-groups x
// 4 col-groups; thread tile = 8 rows x TN cols in registers, k double-buffered.
template <int F>
__global__ __launch_bounds__(256, 2) void k_spmm(
    const float* __restrict__ A0, const float* __restrict__ A1,
    const float* __restrict__ Pm0, const float* __restrict__ Pm1,
    const float* __restrict__ b0, const float* __restrict__ b1,
    float* __restrict__ o0, float* __restrict__ o1, int ostride) {
    constexpr int TN = F / 4;  // cols per thread: 8 (F=32) or 4 (F=16)
    constexpr int PJ = TN / 4; // float4s of P per k: 2 or 1
    const int branch = blockIdx.y;
    const float* __restrict__ A = branch ? A1 : A0;
    const float* __restrict__ Pm = branch ? Pm1 : Pm0;
    const float* __restrict__ bias = branch ? b1 : b0;
    float* __restrict__ o = branch ? o1 : o0;

    const int lane = threadIdx.x & 63;
    const int wave = threadIdx.x >> 6;
    const int kg = lane & 15;   // k-group within wave
    const int cg = lane >> 4;   // col-group 0..3
    const int c0 = cg * TN;
    const int row0 = blockIdx.x * 32 + wave * 8;
    const float* __restrict__ Arow = A + (size_t)row0 * N;

    float acc[8][TN];
#pragma unroll
    for (int m = 0; m < 8; ++m)
#pragma unroll
        for (int j = 0; j < TN; ++j) acc[m][j] = 0.f;

    float4 aA[8], aB[8];
    float4 pA[4][PJ], pB[4][PJ];

    auto load = [&](float4(&a)[8], float4(&p)[4][PJ], int K0) {
        const int kk0 = K0 + kg * 4;
#pragma unroll
        for (int m = 0; m < 8; ++m)
            a[m] = *reinterpret_cast<const float4*>(Arow + (size_t)m * N + kk0);
#pragma unroll
        for (int t = 0; t < 4; ++t)
#pragma unroll
            for (int j = 0; j < PJ; ++j)
                p[t][j] = *reinterpret_cast<const float4*>(Pm + (kk0 + t) * F + c0 + j * 4);
    };
    auto fmas = [&](float4(&a)[8], float4(&p)[4][PJ]) {
#pragma unroll
        for (int m = 0; m < 8; ++m) {
#pragma unroll
            for (int t = 0; t < 4; ++t) {
                const float av = (t == 0) ? a[m].x : (t == 1) ? a[m].y : (t == 2) ? a[m].z : a[m].w;
#pragma unroll
                for (int j = 0; j < PJ; ++j) {
                    acc[m][j * 4 + 0] += av * p[t][j].x;
                    acc[m][j * 4 + 1] += av * p[t][j].y;
                    acc[m][j * 4 + 2] += av * p[t][j].z;
                    acc[m][j * 4 + 3] += av * p[t][j].w;
                }
            }
        }
    };

    load(aA, pA, 0);
    for (int k0 = 0; k0 < N; k0 += 128) {
        load(aB, pB, k0 + 64);
        fmas(aA, pA);
        if (k0 + 128 < N) load(aA, pA, k0 + 128);
        fmas(aB, pB);
    }

    // reduce across the 16 k-groups (lanes kg=0..15 within each cg group)
#pragma unroll
    for (int m = 0; m < 8; ++m)
#pragma unroll
        for (int j = 0; j < TN; ++j) {
            float v = acc[m][j];
            v += __shfl_xor(v, 1);
            v += __shfl_xor(v, 2);
            v += __shfl_xor(v, 4);
            v += __shfl_xor(v, 8);
            acc[m][j] = v;
        }
    if (kg == 0) {
#pragma unroll
        for (int m = 0; m < 8; ++m)
#pragma unroll
            for (int j = 0; j < PJ; ++j) {
                float4 r;
                r.x = fmaxf(acc[m][j * 4 + 0] + bias[c0 + j * 4 + 0], 0.f);
                r.y = fmaxf(acc[m][j * 4 + 1] + bias[c0 + j * 4 + 1], 0.f);
                r.z = fmaxf(acc[m][j * 4 + 2] + bias[c0 + j * 4 + 2], 0.f);
                r.w = fmaxf(acc[m][j * 4 + 3] + bias[c0 + j * 4 + 3], 0.f);
                *reinterpret_cast<float4*>(&o[(size_t)(row0 + m) * ostride + c0 + j * 4]) = r;
            }
    }
}

// ------- kernel 5: per-block partials of Z_h = sum e^{s}, U_h = sum e^{s}(h.Wd_h)
// tanh in [-1,1] -> softmax without max-subtraction is safe.
__global__ void k_att_pool(const float* __restrict__ h, const float* __restrict__ Watt,
                           const float* __restrict__ Wd, float* __restrict__ partials) {
    __shared__ float sWa[64 * 3];
    __shared__ float sWd[192];
    for (int i = threadIdx.x; i < 192; i += blockDim.x) {
        sWa[i] = Watt[i];
        sWd[i] = Wd[i];
    }
    __syncthreads();
    const int n = blockIdx.x * blockDim.x + threadIdx.x;  // 32*256 == N exactly
    float hv[64];
#pragma unroll
    for (int q = 0; q < 16; ++q)
        *reinterpret_cast<float4*>(&hv[q * 4]) =
            *reinterpret_cast<const float4*>(&h[(size_t)n * 64 + q * 4]);
    float s0 = 0.f, s1 = 0.f, s2 = 0.f;
#pragma unroll
    for (int d = 0; d < 64; ++d) {
        s0 += hv[d] * sWa[d * 3 + 0];
        s1 += hv[d] * sWa[d * 3 + 1];
        s2 += hv[d] * sWa[d * 3 + 2];
    }
    float dot0 = 0.f, dot1 = 0.f, dot2 = 0.f;
#pragma unroll
    for (int d = 0; d < 64; ++d) {
        dot0 += hv[d] * sWd[0 * 64 + d];
        dot1 += hv[d] * sWd[1 * 64 + d];
        dot2 += hv[d] * sWd[2 * 64 + d];
    }
    const float e0 = expf(tanhf(s0));
    const float e1 = expf(tanhf(s1));
    const float e2 = expf(tanhf(s2));
    float vals[6] = {e0, e1, e2, e0 * dot0, e1 * dot1, e2 * dot2};
#pragma unroll
    for (int i = 0; i < 6; ++i) {
        float v = vals[i];
#pragma unroll
        for (int off = 1; off < 64; off <<= 1) v += __shfl_xor(v, off);
        vals[i] = v;
    }
    __shared__ float sred[4][6];
    const int wave = threadIdx.x >> 6, lane = threadIdx.x & 63;
    if (lane == 0) {
#pragma unroll
        for (int i = 0; i < 6; ++i) sred[wave][i] = vals[i];
    }
    __syncthreads();
    if (threadIdx.x == 0) {
#pragma unroll
        for (int i = 0; i < 6; ++i)
            partials[blockIdx.x * 6 + i] = sred[0][i] + sred[1][i] + sred[2][i] + sred[3][i];
    }
}

// ------------- kernel 6: out = sum_h U_h/Z_h + b_dense -------------
__global__ void k_att_final(const float* __restrict__ partials, const float* __restrict__ bd,
                            float* __restrict__ out) {
    if (threadIdx.x == 0) {
        float Z0 = 0.f, Z1 = 0.f, Z2 = 0.f, U0 = 0.f, U1 = 0.f, U2 = 0.f;
        for (int b = 0; b < 32; ++b) {
            Z0 += partials[b * 6 + 0];
            Z1 += partials[b * 6 + 1];
            Z2 += partials[b * 6 + 2];
            U0 += partials[b * 6 + 3];
            U1 += partials[b * 6 + 4];
            U2 += partials[b * 6 + 5];
        }
        out[0] = U0 / Z0 + U1 / Z1 + U2 / Z2 + bd[0];
    }
}

extern "C" void kernel_launch(void* const* d_in, const int* in_sizes, int n_in,
                              void* d_out, int out_size, void* d_ws, size_t ws_size,
                              hipStream_t stream) {
    const float* x_int   = (const float*)d_in[0];
    const float* x_nh    = (const float*)d_in[1];
    const float* adj_int = (const float*)d_in[2];
    const float* adj_nh  = (const float*)d_in[3];
    const float* W1_int  = (const float*)d_in[4];
    const float* b1_int  = (const float*)d_in[5];
    const float* W1_nh   = (const float*)d_in[6];
    const float* b1_nh   = (const float*)d_in[7];
    const float* W2_int  = (const float*)d_in[8];
    const float* b2_int  = (const float*)d_in[9];
    const float* W2_nh   = (const float*)d_in[10];
    const float* b2_nh   = (const float*)d_in[11];
    const float* W_att   = (const float*)d_in[12];
    const float* W_dense = (const float*)d_in[13];
    const float* b_dense = (const float*)d_in[14];

    float* ws = (float*)d_ws;
    float* P1_0 = ws;                        // [8192,16]
    float* P1_1 = ws + 131072;
    float* H1_0 = ws + 262144;               // [8192,16]
    float* H1_1 = ws + 393216;
    float* P2_0 = ws + 524288;               // [8192,32]
    float* P2_1 = ws + 786432;
    float* hcat = ws + 1048576;              // [8192,64] = [H2_int | H2_nh]
    float* partials = ws + 1572864;          // [32,6]
    float* out = (float*)d_out;

    k_dense_in<<<dim3(32, 2), 256, 0, stream>>>(x_int, x_nh, W1_int, W1_nh, P1_0, P1_1);
    k_spmm<16><<<dim3(256, 2), 256, 0, stream>>>(adj_int, adj_nh, P1_0, P1_1,
                                                 b1_int, b1_nh, H1_0, H1_1, 16);
    k_dense_mid<<<dim3(32, 2), 256, 0, stream>>>(H1_0, H1_1, W2_int, W2_nh, P2_0, P2_1);
    k_spmm<32><<<dim3(256, 2), 256, 0, stream>>>(adj_int, adj_nh, P2_0, P2_1,
                                                 b2_int, b2_nh, hcat, hcat + 32, 64);
    k_att_pool<<<32, 256, 0, stream>>>(hcat, W_att, W_dense, partials);
    k_att_final<<<1, 64, 0, stream>>>(partials, b_dense, out);
}

// Round 2
// 514.020 us; speedup vs baseline: 1.2662x; 1.2662x over previous
//
#include <hip/hip_runtime.h>

// GNN27: two-branch diffusion GCN (N=8192, F_IN=11, F1=16, F2=32) + multi-head
// tanh-attention pooling. All fp32. Memory-bound on the two 268MB adjacencies,
// each streamed twice (layer1, layer2) -> 1.07GB HBM floor ~170us.
//
// R1 lesson: register-double-buffered direct loads gave 256B-granular access
// across 16K concurrent row-streams -> 680 GB/s (DRAM page thrash). R2: stage
// A tiles through LDS via global_load_lds(16B/lane) so each row advances in
// one contiguous 1KB burst per wave instruction.

constexpr int N = 8192;

#define GLOBAL_AS __attribute__((address_space(1)))
#define LDS_AS __attribute__((address_space(3)))

__device__ __forceinline__ void gload_lds16(const float* g, float* l) {
    __builtin_amdgcn_global_load_lds((const GLOBAL_AS void*)g, (LDS_AS void*)l, 16, 0, 0);
}

// ---------------- kernel 1: P1 = x @ W1   ([N,11] @ [11,16]) ----------------
__global__ void k_dense_in(const float* __restrict__ x0, const float* __restrict__ x1,
                           const float* __restrict__ W0, const float* __restrict__ W1,
                           float* __restrict__ o0, float* __restrict__ o1) {
    const int branch = blockIdx.y;
    const float* __restrict__ x = branch ? x1 : x0;
    const float* __restrict__ W = branch ? W1 : W0;
    float* __restrict__ o = branch ? o1 : o0;
    __shared__ float sW[11 * 16];
    if (threadIdx.x < 176) sW[threadIdx.x] = W[threadIdx.x];
    __syncthreads();
    const int n = blockIdx.x * blockDim.x + threadIdx.x;  // grid.x*256 == N exactly
    float xr[11];
#pragma unroll
    for (int j = 0; j < 11; ++j) xr[j] = x[n * 11 + j];
    float acc[16];
#pragma unroll
    for (int f = 0; f < 16; ++f) acc[f] = 0.f;
#pragma unroll
    for (int j = 0; j < 11; ++j)
#pragma unroll
        for (int f = 0; f < 16; ++f) acc[f] += xr[j] * sW[j * 16 + f];
#pragma unroll
    for (int q = 0; q < 4; ++q) {
        float4 r = make_float4(acc[q * 4 + 0], acc[q * 4 + 1], acc[q * 4 + 2], acc[q * 4 + 3]);
        *reinterpret_cast<float4*>(&o[n * 16 + q * 4]) = r;
    }
}

// ---------------- kernel 3: P2 = H1 @ W2   ([N,16] @ [16,32]) ----------------
__global__ void k_dense_mid(const float* __restrict__ h0, const float* __restrict__ h1,
                            const float* __restrict__ W0, const float* __restrict__ W1,
                            float* __restrict__ o0, float* __restrict__ o1) {
    const int branch = blockIdx.y;
    const float* __restrict__ h = branch ? h1 : h0;
    const float* __restrict__ W = branch ? W1 : W0;
    float* __restrict__ o = branch ? o1 : o0;
    __shared__ float sW[16 * 32];
    for (int i = threadIdx.x; i < 512; i += blockDim.x) sW[i] = W[i];
    __syncthreads();
    const int n = blockIdx.x * blockDim.x + threadIdx.x;
    float hr[16];
#pragma unroll
    for (int q = 0; q < 4; ++q)
        *reinterpret_cast<float4*>(&hr[q * 4]) =
            *reinterpret_cast<const float4*>(&h[n * 16 + q * 4]);
    float acc[32];
#pragma unroll
    for (int f = 0; f < 32; ++f) acc[f] = 0.f;
#pragma unroll
    for (int j = 0; j < 16; ++j)
#pragma unroll
        for (int f = 0; f < 32; ++f) acc[f] += hr[j] * sW[j * 32 + f];
#pragma unroll
    for (int q = 0; q < 8; ++q) {
        float4 r = make_float4(acc[q * 4 + 0], acc[q * 4 + 1], acc[q * 4 + 2], acc[q * 4 + 3]);
        *reinterpret_cast<float4*>(&o[n * 32 + q * 4]) = r;
    }
}

// -------- kernels 2 & 4: H = relu(A @ P + b), A [N,N] streamed via LDS ------
// Block = 256 thr = 4 waves, 32 rows/block. K-tile = 256 floats: each row is
// staged as ONE contiguous 1KB global_load_lds burst per wave instruction.
// Double-buffered LDS (2x32KB). Compute: lane = 16 k-groups x 4 col-groups,
// thread tile = 8 rows x TN cols; A from LDS (ds_read_b128, 2-way = free),
// P from L2 (coalesced 16-consecutive-row reads). Epilogue: 4-round shfl_xor
// reduce over k-groups + bias + relu.
template <int F>
__global__ __launch_bounds__(256, 2) void k_spmm(
    const float* __restrict__ A0, const float* __restrict__ A1,
    const float* __restrict__ Pm0, const float* __restrict__ Pm1,
    const float* __restrict__ b0, const float* __restrict__ b1,
    float* __restrict__ o0, float* __restrict__ o1, int ostride) {
    constexpr int TN = F / 4;   // cols per thread: 8 (F=32) or 4 (F=16)
    constexpr int PJ = TN / 4;  // float4s of P per k: 2 or 1
    constexpr int KT = 256;     // k-tile (floats); 1KB per row per stage
    const int branch = blockIdx.y;
    const float* __restrict__ A = branch ? A1 : A0;
    const float* __restrict__ Pm = branch ? Pm1 : Pm0;
    const float* __restrict__ bias = branch ? b1 : b0;
    float* __restrict__ o = branch ? o1 : o0;

    __shared__ float tile[2][32 * KT];  // 64 KB

    const int lane = threadIdx.x & 63;
    const int wave = threadIdx.x >> 6;
    const int kg = lane & 15;  // k-group within wave
    const int cg = lane >> 4;  // col-group 0..3
    const int c0 = cg * TN;
    const int row0 = blockIdx.x * 32;

    // staging: wave w loads rows w*8..w*8+7; per row one 1KB burst (lane*16B)
    const float* gbase = A + (size_t)(row0 + wave * 8) * N + lane * 4;

    float acc[8][TN];
#pragma unroll
    for (int m = 0; m < 8; ++m)
#pragma unroll
        for (int j = 0; j < TN; ++j) acc[m][j] = 0.f;

    auto stage = [&](int buf, int K0) {
#pragma unroll
        for (int r = 0; r < 8; ++r)
            gload_lds16(gbase + (size_t)r * N + K0, &tile[buf][(wave * 8 + r) * KT]);
    };

    auto compute = [&](int buf, int K0) {
#pragma unroll
        for (int ks = 0; ks < 4; ++ks) {
            const int kk = ks * 64 + kg * 4;  // k within tile for this thread
            float4 p[4][PJ];
#pragma unroll
            for (int t = 0; t < 4; ++t)
#pragma unroll
                for (int j = 0; j < PJ; ++j)
                    p[t][j] = *reinterpret_cast<const float4*>(
                        Pm + (size_t)(K0 + kk + t) * F + c0 + j * 4);
#pragma unroll
            for (int m = 0; m < 8; ++m) {
                const float4 a = *reinterpret_cast<const float4*>(
                    &tile[buf][(wave * 8 + m) * KT + kk]);
#pragma unroll
                for (int t = 0; t < 4; ++t) {
                    const float av = (t == 0) ? a.x : (t == 1) ? a.y : (t == 2) ? a.z : a.w;
#pragma unroll
                    for (int j = 0; j < PJ; ++j) {
                        acc[m][j * 4 + 0] += av * p[t][j].x;
                        acc[m][j * 4 + 1] += av * p[t][j].y;
                        acc[m][j * 4 + 2] += av * p[t][j].z;
                        acc[m][j * 4 + 3] += av * p[t][j].w;
                    }
                }
            }
        }
    };

    stage(0, 0);
    __syncthreads();  // vmcnt(0) drain -> buf0 ready
    int cur = 0;
    for (int K0 = 0; K0 < N; K0 += KT) {
        if (K0 + KT < N) stage(cur ^ 1, K0 + KT);  // async, overlaps compute
        compute(cur, K0);
        __syncthreads();  // drains stage loads; guards buffer reuse
        cur ^= 1;
    }

    // reduce across the 16 k-groups
#pragma unroll
    for (int m = 0; m < 8; ++m)
#pragma unroll
        for (int j = 0; j < TN; ++j) {
            float v = acc[m][j];
            v += __shfl_xor(v, 1);
            v += __shfl_xor(v, 2);
            v += __shfl_xor(v, 4);
            v += __shfl_xor(v, 8);
            acc[m][j] = v;
        }
    if (kg == 0) {
#pragma unroll
        for (int m = 0; m < 8; ++m)
#pragma unroll
            for (int j = 0; j < PJ; ++j) {
                float4 r;
                r.x = fmaxf(acc[m][j * 4 + 0] + bias[c0 + j * 4 + 0], 0.f);
                r.y = fmaxf(acc[m][j * 4 + 1] + bias[c0 + j * 4 + 1], 0.f);
                r.z = fmaxf(acc[m][j * 4 + 2] + bias[c0 + j * 4 + 2], 0.f);
                r.w = fmaxf(acc[m][j * 4 + 3] + bias[c0 + j * 4 + 3], 0.f);
                *reinterpret_cast<float4*>(
                    &o[(size_t)(row0 + wave * 8 + m) * ostride + c0 + j * 4]) = r;
            }
    }
}

// ------- kernel 5: per-block partials of Z_h = sum e^{s}, U_h = sum e^{s}(h.Wd_h)
// tanh in [-1,1] -> softmax without max-subtraction is safe.
__global__ void k_att_pool(const float* __restrict__ h, const float* __restrict__ Watt,
                           const float* __restrict__ Wd, float* __restrict__ partials) {
    __shared__ float sWa[64 * 3];
    __shared__ float sWd[192];
    for (int i = threadIdx.x; i < 192; i += blockDim.x) {
        sWa[i] = Watt[i];
        sWd[i] = Wd[i];
    }
    __syncthreads();
    const int n = blockIdx.x * blockDim.x + threadIdx.x;  // 32*256 == N exactly
    float hv[64];
#pragma unroll
    for (int q = 0; q < 16; ++q)
        *reinterpret_cast<float4*>(&hv[q * 4]) =
            *reinterpret_cast<const float4*>(&h[(size_t)n * 64 + q * 4]);
    float s0 = 0.f, s1 = 0.f, s2 = 0.f;
#pragma unroll
    for (int d = 0; d < 64; ++d) {
        s0 += hv[d] * sWa[d * 3 + 0];
        s1 += hv[d] * sWa[d * 3 + 1];
        s2 += hv[d] * sWa[d * 3 + 2];
    }
    float dot0 = 0.f, dot1 = 0.f, dot2 = 0.f;
#pragma unroll
    for (int d = 0; d < 64; ++d) {
        dot0 += hv[d] * sWd[0 * 64 + d];
        dot1 += hv[d] * sWd[1 * 64 + d];
        dot2 += hv[d] * sWd[2 * 64 + d];
    }
    const float e0 = expf(tanhf(s0));
    const float e1 = expf(tanhf(s1));
    const float e2 = expf(tanhf(s2));
    float vals[6] = {e0, e1, e2, e0 * dot0, e1 * dot1, e2 * dot2};
#pragma unroll
    for (int i = 0; i < 6; ++i) {
        float v = vals[i];
#pragma unroll
        for (int off = 1; off < 64; off <<= 1) v += __shfl_xor(v, off);
        vals[i] = v;
    }
    __shared__ float sred[4][6];
    const int wave = threadIdx.x >> 6, lane = threadIdx.x & 63;
    if (lane == 0) {
#pragma unroll
        for (int i = 0; i < 6; ++i) sred[wave][i] = vals[i];
    }
    __syncthreads();
    if (threadIdx.x == 0) {
#pragma unroll
        for (int i = 0; i < 6; ++i)
            partials[blockIdx.x * 6 + i] = sred[0][i] + sred[1][i] + sred[2][i] + sred[3][i];
    }
}

// ------------- kernel 6: out = sum_h U_h/Z_h + b_dense -------------
__global__ void k_att_final(const float* __restrict__ partials, const float* __restrict__ bd,
                            float* __restrict__ out) {
    if (threadIdx.x == 0) {
        float Z0 = 0.f, Z1 = 0.f, Z2 = 0.f, U0 = 0.f, U1 = 0.f, U2 = 0.f;
        for (int b = 0; b < 32; ++b) {
            Z0 += partials[b * 6 + 0];
            Z1 += partials[b * 6 + 1];
            Z2 += partials[b * 6 + 2];
            U0 += partials[b * 6 + 3];
            U1 += partials[b * 6 + 4];
            U2 += partials[b * 6 + 5];
        }
        out[0] = U0 / Z0 + U1 / Z1 + U2 / Z2 + bd[0];
    }
}

extern "C" void kernel_launch(void* const* d_in, const int* in_sizes, int n_in,
                              void* d_out, int out_size, void* d_ws, size_t ws_size,
                              hipStream_t stream) {
    const float* x_int   = (const float*)d_in[0];
    const float* x_nh    = (const float*)d_in[1];
    const float* adj_int = (const float*)d_in[2];
    const float* adj_nh  = (const float*)d_in[3];
    const float* W1_int  = (const float*)d_in[4];
    const float* b1_int  = (const float*)d_in[5];
    const float* W1_nh   = (const float*)d_in[6];
    const float* b1_nh   = (const float*)d_in[7];
    const float* W2_int  = (const float*)d_in[8];
    const float* b2_int  = (const float*)d_in[9];
    const float* W2_nh   = (const float*)d_in[10];
    const float* b2_nh   = (const float*)d_in[11];
    const float* W_att   = (const float*)d_in[12];
    const float* W_dense = (const float*)d_in[13];
    const float* b_dense = (const float*)d_in[14];

    float* ws = (float*)d_ws;
    float* P1_0 = ws;                        // [8192,16]
    float* P1_1 = ws + 131072;
    float* H1_0 = ws + 262144;               // [8192,16]
    float* H1_1 = ws + 393216;
    float* P2_0 = ws + 524288;               // [8192,32]
    float* P2_1 = ws + 786432;
    float* hcat = ws + 1048576;              // [8192,64] = [H2_int | H2_nh]
    float* partials = ws + 1572864;          // [32,6]
    float* out = (float*)d_out;

    k_dense_in<<<dim3(32, 2), 256, 0, stream>>>(x_int, x_nh, W1_int, W1_nh, P1_0, P1_1);
    k_spmm<16><<<dim3(256, 2), 256, 0, stream>>>(adj_int, adj_nh, P1_0, P1_1,
                                                 b1_int, b1_nh, H1_0, H1_1, 16);
    k_dense_mid<<<dim3(32, 2), 256, 0, stream>>>(H1_0, H1_1, W2_int, W2_nh, P2_0, P2_1);
    k_spmm<32><<<dim3(256, 2), 256, 0, stream>>>(adj_int, adj_nh, P2_0, P2_1,
                                                 b2_int, b2_nh, hcat, hcat + 32, 64);
    k_att_pool<<<32, 256, 0, stream>>>(hcat, W_att, W_dense, partials);
    k_att_final<<<1, 64, 0, stream>>>(partials, b_dense, out);
}